// Round 1
// baseline (177.385 us; speedup 1.0000x reference)
//
#include <hip/hip_runtime.h>
#include <math.h>

#define BATCH 16
#define T 20
#define NA 3
#define NC 80
#define NH 76
#define NW 76
#define HW (NH*NW)
#define P (NA*HW)
#define STRIDE 8.0f
#define EPSI 1e-9f

__device__ __constant__ float ANC[18] = {
    10.f,13.f, 16.f,30.f, 33.f,23.f, 30.f,61.f, 62.f,45.f,
    59.f,119.f, 116.f,90.f, 156.f,198.f, 373.f,326.f
};

__global__ __launch_bounds__(256) void yolo_loss_kernel(
    const float* __restrict__ x,
    const float* __restrict__ tg,
    float* __restrict__ out)
{
    __shared__ float s_gt[T][4];    // gt cx,cy,w,h in px (w=0 -> invalid)
    __shared__ int   s_flat[T];     // matched cell index or -1
    __shared__ float s_info[T][6];  // tx,ty,lw,lh,cls,scale
    __shared__ float s_red[4][3];

    const int b   = blockIdx.y;
    const int tid = threadIdx.x;

    // ---- per-target matching table (tiny, recomputed per block) ----
    if (tid < T) {
        const float* tp = tg + (b*T + tid)*5;
        float cxn = tp[0], cyn = tp[1], wn = tp[2], hn = tp[3], cls = tp[4];
        float gcx = cxn*608.f, gcy = cyn*608.f, gw = wn*608.f, gh = hn*608.f;
        bool valid = wn > 0.0f;
        s_gt[tid][0] = gcx; s_gt[tid][1] = gcy;
        s_gt[tid][2] = valid ? gw : 0.0f; s_gt[tid][3] = gh;

        // best anchor over all 9 (first-max wins, like jnp.argmax)
        int best = 0; float bestv = -1.0f;
        #pragma unroll
        for (int k = 0; k < 9; k++) {
            float aw = ANC[2*k], ah = ANC[2*k+1];
            float inter = fminf(gw, aw) * fminf(gh, ah);
            float v = inter / (gw*gh + aw*ah - inter + EPSI);
            if (v > bestv) { bestv = v; best = k; }
        }
        bool ok = valid && (best <= 2);
        int gi = (int)floorf(gcx / STRIDE); gi = min(max(gi, 0), NW-1);
        int gj = (int)floorf(gcy / STRIDE); gj = min(max(gj, 0), NH-1);
        s_flat[tid] = ok ? (best*HW + gj*NW + gi) : -1;
        float aw = ANC[2*best], ah = ANC[2*best+1];
        float sw = ok ? gw : 1.0f, sh = ok ? gh : 1.0f;
        s_info[tid][0] = gcx / STRIDE - (float)gi;
        s_info[tid][1] = gcy / STRIDE - (float)gj;
        s_info[tid][2] = logf(sw / aw);
        s_info[tid][3] = logf(sh / ah);
        s_info[tid][4] = cls;
        s_info[tid][5] = 2.0f - wn*hn;
    }
    __syncthreads();

    const int idx = blockIdx.x * blockDim.x + tid;
    float loc = 0.0f, conf = 0.0f, clsl = 0.0f;

    if (idx < P) {
        int a  = idx / HW;
        int hw = idx - a*HW;
        int hh = hw / NW;
        int ww = hw - hh*NW;

        const float* xb = x + ((size_t)b*NA*(5+NC) + (size_t)a*(5+NC)) * HW + hw;
        float z0 = xb[0*HW], z1 = xb[1*HW], z2 = xb[2*HW], z3 = xb[3*HW], z4 = xb[4*HW];

        float sx = 1.0f / (1.0f + expf(-z0));
        float sy = 1.0f / (1.0f + expf(-z1));
        float cx = (sx + (float)ww) * STRIDE;
        float cy = (sy + (float)hh) * STRIDE;
        float aw = ANC[2*a], ah = ANC[2*a+1];
        float bw = expf(z2) * aw, bh = expf(z3) * ah;
        float ax1 = cx - 0.5f*bw, ay1 = cy - 0.5f*bh;
        float ax2 = cx + 0.5f*bw, ay2 = cy + 0.5f*bh;
        float areaa = bw * bh;

        // max IoU vs GT boxes -> ignore mask
        float maxiou = 0.0f;
        #pragma unroll
        for (int t = 0; t < T; t++) {
            float gw = s_gt[t][2];
            if (gw <= 0.0f) continue;
            float gcx = s_gt[t][0], gcy = s_gt[t][1], gh = s_gt[t][3];
            float bx1 = gcx - 0.5f*gw, by1 = gcy - 0.5f*gh;
            float bx2 = gcx + 0.5f*gw, by2 = gcy + 0.5f*gh;
            float iw = fmaxf(fminf(ax2, bx2) - fmaxf(ax1, bx1), 0.0f);
            float ih = fmaxf(fminf(ay2, by2) - fmaxf(ay1, by1), 0.0f);
            float inter = iw * ih;
            float iou = inter / (areaa + gw*gh - inter + EPSI);
            maxiou = fmaxf(maxiou, iou);
        }
        bool ignore = maxiou > 0.5f;

        // scatter emulation: ascending scan, last match wins (numpy semantics)
        int mt = -1;
        #pragma unroll
        for (int t = 0; t < T; t++) if (s_flat[t] == idx) mt = t;

        float pconf = 1.0f / (1.0f + expf(-z4));
        if (mt >= 0) {
            conf = -logf(fmaxf(pconf, 1e-12f));
            float tx = s_info[mt][0], ty = s_info[mt][1];
            float lw = s_info[mt][2], lh = s_info[mt][3];
            int   ci = (int)s_info[mt][4];
            float sc = s_info[mt][5];
            float dx = sx - tx, dy = sy - ty, dw = z2 - lw, dh = z3 - lh;
            loc = 0.5f * sc * (dx*dx + dy*dy + dw*dw + dh*dh);
            float cs = 0.0f;
            for (int c = 0; c < NC; c++) {
                float z  = xb[(5 + c) * HW];
                float pc = 1.0f / (1.0f + expf(-z));
                cs += (c == ci) ? -logf(fmaxf(pc, 1e-12f))
                                : -logf(fmaxf(1.0f - pc, 1e-12f));
            }
            clsl = cs;
        } else if (!ignore) {
            conf = -logf(fmaxf(1.0f - pconf, 1e-12f));
        }
    }

    // ---- block reduction (wave64 shuffle, then LDS across 4 waves) ----
    #pragma unroll
    for (int off = 32; off > 0; off >>= 1) {
        loc  += __shfl_down(loc,  off, 64);
        conf += __shfl_down(conf, off, 64);
        clsl += __shfl_down(clsl, off, 64);
    }
    int lane = tid & 63, wid = tid >> 6;
    if (lane == 0) { s_red[wid][0] = loc; s_red[wid][1] = conf; s_red[wid][2] = clsl; }
    __syncthreads();
    if (tid == 0) {
        float l = 0.f, c = 0.f, k = 0.f;
        #pragma unroll
        for (int i = 0; i < 4; i++) { l += s_red[i][0]; c += s_red[i][1]; k += s_red[i][2]; }
        const float inv_b = 1.0f / (float)BATCH;
        atomicAdd(&out[0], l * inv_b);
        atomicAdd(&out[1], c * inv_b);
        atomicAdd(&out[2], k * inv_b);
    }
}

extern "C" void kernel_launch(void* const* d_in, const int* in_sizes, int n_in,
                              void* d_out, int out_size, void* d_ws, size_t ws_size,
                              hipStream_t stream) {
    const float* x  = (const float*)d_in[0];
    const float* tg = (const float*)d_in[1];
    float* out = (float*)d_out;

    hipMemsetAsync(out, 0, 3 * sizeof(float), stream);

    dim3 grid((P + 255) / 256, BATCH);
    yolo_loss_kernel<<<grid, 256, 0, stream>>>(x, tg, out);
}

// Round 2
// 161.860 us; speedup vs baseline: 1.0959x; 1.0959x over previous
//
#include <hip/hip_runtime.h>
#include <math.h>

#define BATCH 16
#define T 20
#define NA 3
#define NC 80
#define NH 76
#define NW 76
#define HW (NH*NW)
#define P (NA*HW)
#define STRIDE 8.0f
#define EPSI 1e-9f

__device__ __constant__ float ANC[18] = {
    10.f,13.f, 16.f,30.f, 33.f,23.f, 30.f,61.f, 62.f,45.f,
    59.f,119.f, 116.f,90.f, 156.f,198.f, 373.f,326.f
};

__global__ __launch_bounds__(256) void yolo_loss_kernel(
    const float* __restrict__ x,
    const float* __restrict__ tg,
    float* __restrict__ out)
{
    __shared__ float s_gt[T][4];    // gt cx,cy,w,h in px (w=0 -> invalid)
    __shared__ int   s_flat[T];     // matched cell index or -1
    __shared__ float s_info[T][6];  // tx,ty,lw,lh,cls,scale
    __shared__ float s_red[4][3];
    __shared__ int   s_fcnt;        // fore-cell queue for cooperative cls-BCE
    __shared__ int   s_fbase[T];    // element offset of fore cell in x
    __shared__ int   s_fci[T];      // its target class

    const int b   = blockIdx.y;
    const int tid = threadIdx.x;
    const int idx = blockIdx.x * blockDim.x + tid;
    const bool active = (idx < P);

    // ---- issue the 5 coalesced channel loads FIRST (in flight during setup) ----
    int a = 0, hw = 0;
    const float* xb = x;
    float z0 = 0.f, z1 = 0.f, z2 = 0.f, z3 = 0.f, z4 = 0.f;
    if (active) {
        a  = idx / HW;
        hw = idx - a*HW;
        xb = x + ((size_t)b*NA*(5+NC) + (size_t)a*(5+NC)) * HW + hw;
        z0 = xb[0*HW]; z1 = xb[1*HW]; z2 = xb[2*HW]; z3 = xb[3*HW]; z4 = xb[4*HW];
    }

    // ---- per-target matching table (tiny, recomputed per block) ----
    if (tid == 0) s_fcnt = 0;
    if (tid < T) {
        const float* tp = tg + (b*T + tid)*5;
        float cxn = tp[0], cyn = tp[1], wn = tp[2], hn = tp[3], cls = tp[4];
        float gcx = cxn*608.f, gcy = cyn*608.f, gw = wn*608.f, gh = hn*608.f;
        bool valid = wn > 0.0f;
        s_gt[tid][0] = gcx; s_gt[tid][1] = gcy;
        s_gt[tid][2] = valid ? gw : 0.0f; s_gt[tid][3] = gh;

        int best = 0; float bestv = -1.0f;
        #pragma unroll
        for (int k = 0; k < 9; k++) {
            float aw = ANC[2*k], ah = ANC[2*k+1];
            float inter = fminf(gw, aw) * fminf(gh, ah);
            float v = inter / (gw*gh + aw*ah - inter + EPSI);
            if (v > bestv) { bestv = v; best = k; }
        }
        bool ok = valid && (best <= 2);
        int gi = (int)floorf(gcx / STRIDE); gi = min(max(gi, 0), NW-1);
        int gj = (int)floorf(gcy / STRIDE); gj = min(max(gj, 0), NH-1);
        s_flat[tid] = ok ? (best*HW + gj*NW + gi) : -1;
        float aw = ANC[2*best], ah = ANC[2*best+1];
        float sw = ok ? gw : 1.0f, sh = ok ? gh : 1.0f;
        s_info[tid][0] = gcx / STRIDE - (float)gi;
        s_info[tid][1] = gcy / STRIDE - (float)gj;
        s_info[tid][2] = logf(sw / aw);
        s_info[tid][3] = logf(sh / ah);
        s_info[tid][4] = cls;
        s_info[tid][5] = 2.0f - wn*hn;
    }
    __syncthreads();

    float loc = 0.0f, conf = 0.0f, clsl = 0.0f;

    if (active) {
        int hh = hw / NW;
        int ww = hw - hh*NW;

        float sx = 1.0f / (1.0f + expf(-z0));
        float sy = 1.0f / (1.0f + expf(-z1));
        float cx = (sx + (float)ww) * STRIDE;
        float cy = (sy + (float)hh) * STRIDE;
        float aw = ANC[2*a], ah = ANC[2*a+1];
        float bw = expf(z2) * aw, bh = expf(z3) * ah;
        float ax1 = cx - 0.5f*bw, ay1 = cy - 0.5f*bh;
        float ax2 = cx + 0.5f*bw, ay2 = cy + 0.5f*bh;
        float areaa = bw * bh;

        // max IoU vs GT boxes -> ignore mask
        float maxiou = 0.0f;
        #pragma unroll
        for (int t = 0; t < T; t++) {
            float gw = s_gt[t][2];
            if (gw <= 0.0f) continue;
            float gcx = s_gt[t][0], gcy = s_gt[t][1], gh = s_gt[t][3];
            float bx1 = gcx - 0.5f*gw, by1 = gcy - 0.5f*gh;
            float bx2 = gcx + 0.5f*gw, by2 = gcy + 0.5f*gh;
            float iw = fmaxf(fminf(ax2, bx2) - fmaxf(ax1, bx1), 0.0f);
            float ih = fmaxf(fminf(ay2, by2) - fmaxf(ay1, by1), 0.0f);
            float inter = iw * ih;
            float iou = inter / (areaa + gw*gh - inter + EPSI);
            maxiou = fmaxf(maxiou, iou);
        }
        bool ignore = maxiou > 0.5f;

        // scatter emulation: ascending scan, last match wins
        int mt = -1;
        #pragma unroll
        for (int t = 0; t < T; t++) if (s_flat[t] == idx) mt = t;

        float pconf = 1.0f / (1.0f + expf(-z4));
        if (mt >= 0) {
            conf = -logf(fmaxf(pconf, 1e-12f));
            float tx = s_info[mt][0], ty = s_info[mt][1];
            float lw = s_info[mt][2], lh = s_info[mt][3];
            float sc = s_info[mt][5];
            float dx = sx - tx, dy = sy - ty, dw = z2 - lw, dh = z3 - lh;
            loc = 0.5f * sc * (dx*dx + dy*dy + dw*dw + dh*dh);
            // enqueue for cooperative class-BCE (parallel loads, no 80-deep
            // serialized latency chain in one lane)
            int slot = atomicAdd(&s_fcnt, 1);
            s_fbase[slot] = (int)(((size_t)b*NA + a)*(5+NC)*HW + hw);
            s_fci[slot]   = (int)s_info[mt][4];
        } else if (!ignore) {
            conf = -logf(fmaxf(1.0f - pconf, 1e-12f));
        }
    }

    // ---- cooperative class-BCE: 80 lanes per fore cell, one latency trip ----
    __syncthreads();
    int nf = s_fcnt;
    for (int f = 0; f < nf; f++) {
        if (tid < NC) {
            float z  = x[s_fbase[f] + (5 + tid) * HW];
            float pc = 1.0f / (1.0f + expf(-z));
            clsl += (tid == s_fci[f]) ? -logf(fmaxf(pc, 1e-12f))
                                      : -logf(fmaxf(1.0f - pc, 1e-12f));
        }
    }

    // ---- block reduction (wave64 shuffle, then LDS across 4 waves) ----
    #pragma unroll
    for (int off = 32; off > 0; off >>= 1) {
        loc  += __shfl_down(loc,  off, 64);
        conf += __shfl_down(conf, off, 64);
        clsl += __shfl_down(clsl, off, 64);
    }
    int lane = tid & 63, wid = tid >> 6;
    if (lane == 0) { s_red[wid][0] = loc; s_red[wid][1] = conf; s_red[wid][2] = clsl; }
    __syncthreads();
    if (tid == 0) {
        float l = 0.f, c = 0.f, k = 0.f;
        #pragma unroll
        for (int i = 0; i < 4; i++) { l += s_red[i][0]; c += s_red[i][1]; k += s_red[i][2]; }
        const float inv_b = 1.0f / (float)BATCH;
        atomicAdd(&out[0], l * inv_b);
        atomicAdd(&out[1], c * inv_b);
        atomicAdd(&out[2], k * inv_b);
    }
}

extern "C" void kernel_launch(void* const* d_in, const int* in_sizes, int n_in,
                              void* d_out, int out_size, void* d_ws, size_t ws_size,
                              hipStream_t stream) {
    const float* x  = (const float*)d_in[0];
    const float* tg = (const float*)d_in[1];
    float* out = (float*)d_out;

    hipMemsetAsync(out, 0, 3 * sizeof(float), stream);

    dim3 grid((P + 255) / 256, BATCH);
    yolo_loss_kernel<<<grid, 256, 0, stream>>>(x, tg, out);
}

// Round 3
// 127.857 us; speedup vs baseline: 1.3874x; 1.2659x over previous
//
#include <hip/hip_runtime.h>
#include <math.h>

#define BATCH 16
#define T 20
#define NA 3
#define NC 80
#define NH 76
#define NW 76
#define HW (NH*NW)
#define P (NA*HW)
#define STRIDE 8.0f
#define EPSI 1e-9f
#define VCELLS 2
#define BLOCKSX 34              // 34*256*2 = 17408 >= P
#define CHUNK (BLOCKSX*256)     // 8704
#define NPART (BLOCKSX*BATCH)   // 544

__device__ __constant__ float ANC[18] = {
    10.f,13.f, 16.f,30.f, 33.f,23.f, 30.f,61.f, 62.f,45.f,
    59.f,119.f, 116.f,90.f, 156.f,198.f, 373.f,326.f
};

__global__ __launch_bounds__(256) void yolo_partial(
    const float* __restrict__ x,
    const float* __restrict__ tg,
    float* __restrict__ part)   // [NPART][3] plain stores, no atomics
{
    __shared__ float s_gt[T][4];
    __shared__ int   s_flat[T];
    __shared__ float s_info[T][6];
    __shared__ float s_red[4][3];
    __shared__ int   s_fcnt;
    __shared__ int   s_fbase[T + 4];
    __shared__ int   s_fci[T + 4];

    const int b   = blockIdx.y;
    const int tid = threadIdx.x;
    const int base = blockIdx.x * 256 + tid;

    // ---- issue all channel loads first (max memory-level parallelism) ----
    float z[VCELLS][5];
    int   aarr[VCELLS], hwarr[VCELLS];
    bool  act[VCELLS];
    #pragma unroll
    for (int k = 0; k < VCELLS; k++) {
        int idx = base + k * CHUNK;
        act[k] = (idx < P);
        aarr[k] = 0; hwarr[k] = 0;
        #pragma unroll
        for (int c = 0; c < 5; c++) z[k][c] = 0.0f;
        if (act[k]) {
            int a  = idx / HW;
            int hw = idx - a * HW;
            aarr[k] = a; hwarr[k] = hw;
            const float* xb = x + ((size_t)b * NA * (5 + NC) + (size_t)a * (5 + NC)) * HW + hw;
            #pragma unroll
            for (int c = 0; c < 5; c++) z[k][c] = xb[c * HW];
        }
    }

    // ---- per-target matching table ----
    if (tid == 0) s_fcnt = 0;
    if (tid < T) {
        const float* tp = tg + (b * T + tid) * 5;
        float cxn = tp[0], cyn = tp[1], wn = tp[2], hn = tp[3], cls = tp[4];
        float gcx = cxn * 608.f, gcy = cyn * 608.f, gw = wn * 608.f, gh = hn * 608.f;
        bool valid = wn > 0.0f;
        s_gt[tid][0] = gcx; s_gt[tid][1] = gcy;
        s_gt[tid][2] = valid ? gw : 0.0f; s_gt[tid][3] = gh;

        int best = 0; float bestv = -1.0f;
        #pragma unroll
        for (int k = 0; k < 9; k++) {
            float aw = ANC[2 * k], ah = ANC[2 * k + 1];
            float inter = fminf(gw, aw) * fminf(gh, ah);
            float v = inter / (gw * gh + aw * ah - inter + EPSI);
            if (v > bestv) { bestv = v; best = k; }
        }
        bool ok = valid && (best <= 2);
        int gi = (int)floorf(gcx / STRIDE); gi = min(max(gi, 0), NW - 1);
        int gj = (int)floorf(gcy / STRIDE); gj = min(max(gj, 0), NH - 1);
        s_flat[tid] = ok ? (best * HW + gj * NW + gi) : -1;
        float aw = ANC[2 * best], ah = ANC[2 * best + 1];
        float sw = ok ? gw : 1.0f, sh = ok ? gh : 1.0f;
        s_info[tid][0] = gcx / STRIDE - (float)gi;
        s_info[tid][1] = gcy / STRIDE - (float)gj;
        s_info[tid][2] = logf(sw / aw);
        s_info[tid][3] = logf(sh / ah);
        s_info[tid][4] = cls;
        s_info[tid][5] = 2.0f - wn * hn;
    }
    __syncthreads();

    float loc = 0.0f, conf = 0.0f, clsl = 0.0f;

    #pragma unroll
    for (int k = 0; k < VCELLS; k++) {
        if (!act[k]) continue;
        int idx = base + k * CHUNK;
        int a = aarr[k], hw = hwarr[k];
        int hh = hw / NW;
        int ww = hw - hh * NW;

        float sx = 1.0f / (1.0f + expf(-z[k][0]));
        float sy = 1.0f / (1.0f + expf(-z[k][1]));
        float cx = (sx + (float)ww) * STRIDE;
        float cy = (sy + (float)hh) * STRIDE;
        float aw = ANC[2 * a], ah = ANC[2 * a + 1];
        float bw = expf(z[k][2]) * aw, bh = expf(z[k][3]) * ah;
        float ax1 = cx - 0.5f * bw, ay1 = cy - 0.5f * bh;
        float ax2 = cx + 0.5f * bw, ay2 = cy + 0.5f * bh;
        float areaa = bw * bh;

        float maxiou = 0.0f;
        #pragma unroll
        for (int t = 0; t < T; t++) {
            float gw = s_gt[t][2];
            if (gw <= 0.0f) continue;
            float gcx = s_gt[t][0], gcy = s_gt[t][1], gh = s_gt[t][3];
            float bx1 = gcx - 0.5f * gw, by1 = gcy - 0.5f * gh;
            float bx2 = gcx + 0.5f * gw, by2 = gcy + 0.5f * gh;
            float iw = fmaxf(fminf(ax2, bx2) - fmaxf(ax1, bx1), 0.0f);
            float ih = fmaxf(fminf(ay2, by2) - fmaxf(ay1, by1), 0.0f);
            float inter = iw * ih;
            float iou = inter / (areaa + gw * gh - inter + EPSI);
            maxiou = fmaxf(maxiou, iou);
        }
        bool ignore = maxiou > 0.5f;

        int mt = -1;
        #pragma unroll
        for (int t = 0; t < T; t++) if (s_flat[t] == idx) mt = t;

        float pconf = 1.0f / (1.0f + expf(-z[k][4]));
        if (mt >= 0) {
            conf += -logf(fmaxf(pconf, 1e-12f));
            float tx = s_info[mt][0], ty = s_info[mt][1];
            float lw = s_info[mt][2], lh = s_info[mt][3];
            float sc = s_info[mt][5];
            float dx = sx - tx, dy = sy - ty, dw = z[k][2] - lw, dh = z[k][3] - lh;
            loc += 0.5f * sc * (dx * dx + dy * dy + dw * dw + dh * dh);
            int slot = atomicAdd(&s_fcnt, 1);          // LDS atomic, cheap
            s_fbase[slot] = (int)(((size_t)b * NA + a) * (5 + NC) * HW + hw);
            s_fci[slot]   = (int)s_info[mt][4];
        } else if (!ignore) {
            conf += -logf(fmaxf(1.0f - pconf, 1e-12f));
        }
    }

    // ---- cooperative class-BCE: 80 lanes per fore cell ----
    __syncthreads();
    int nf = s_fcnt;
    for (int f = 0; f < nf; f++) {
        if (tid < NC) {
            float zc = x[s_fbase[f] + (5 + tid) * HW];
            float pc = 1.0f / (1.0f + expf(-zc));
            clsl += (tid == s_fci[f]) ? -logf(fmaxf(pc, 1e-12f))
                                      : -logf(fmaxf(1.0f - pc, 1e-12f));
        }
    }

    // ---- block reduction ----
    #pragma unroll
    for (int off = 32; off > 0; off >>= 1) {
        loc  += __shfl_down(loc,  off, 64);
        conf += __shfl_down(conf, off, 64);
        clsl += __shfl_down(clsl, off, 64);
    }
    int lane = tid & 63, wid = tid >> 6;
    if (lane == 0) { s_red[wid][0] = loc; s_red[wid][1] = conf; s_red[wid][2] = clsl; }
    __syncthreads();
    if (tid == 0) {
        float l = 0.f, c = 0.f, k = 0.f;
        #pragma unroll
        for (int i = 0; i < 4; i++) { l += s_red[i][0]; c += s_red[i][1]; k += s_red[i][2]; }
        float* pp = part + (blockIdx.y * BLOCKSX + blockIdx.x) * 3;
        pp[0] = l; pp[1] = c; pp[2] = k;       // plain stores, zero contention
    }
}

__global__ __launch_bounds__(256) void yolo_reduce(
    const float* __restrict__ part,
    float* __restrict__ out)
{
    __shared__ float s_red[4][3];
    const int tid = threadIdx.x;
    float l = 0.f, c = 0.f, k = 0.f;
    for (int i = tid; i < NPART; i += 256) {
        l += part[i * 3 + 0];
        c += part[i * 3 + 1];
        k += part[i * 3 + 2];
    }
    #pragma unroll
    for (int off = 32; off > 0; off >>= 1) {
        l += __shfl_down(l, off, 64);
        c += __shfl_down(c, off, 64);
        k += __shfl_down(k, off, 64);
    }
    int lane = tid & 63, wid = tid >> 6;
    if (lane == 0) { s_red[wid][0] = l; s_red[wid][1] = c; s_red[wid][2] = k; }
    __syncthreads();
    if (tid == 0) {
        float ll = 0.f, cc = 0.f, kk = 0.f;
        #pragma unroll
        for (int i = 0; i < 4; i++) { ll += s_red[i][0]; cc += s_red[i][1]; kk += s_red[i][2]; }
        const float inv_b = 1.0f / (float)BATCH;
        out[0] = ll * inv_b;
        out[1] = cc * inv_b;
        out[2] = kk * inv_b;
    }
}

extern "C" void kernel_launch(void* const* d_in, const int* in_sizes, int n_in,
                              void* d_out, int out_size, void* d_ws, size_t ws_size,
                              hipStream_t stream) {
    const float* x  = (const float*)d_in[0];
    const float* tg = (const float*)d_in[1];
    float* out  = (float*)d_out;
    float* part = (float*)d_ws;

    dim3 grid(BLOCKSX, BATCH);
    yolo_partial<<<grid, 256, 0, stream>>>(x, tg, part);
    yolo_reduce<<<1, 256, 0, stream>>>(part, out);
}